// Round 15
// baseline (283.690 us; speedup 1.0000x reference)
//
#include <hip/hip_runtime.h>
#include <cstddef>

#define D_FEAT 64
#define S_DIM 16
#define H_DIM 32
#define OUT_DIM 16
#define MAX_IT 5

typedef _Float16 half8 __attribute__((ext_vector_type(8)));
typedef _Float16 f16x8 __attribute__((ext_vector_type(8)));
typedef float f32x4 __attribute__((ext_vector_type(4)));

__device__ __forceinline__ float fast_tanh(float x) {
    float xc = fminf(fmaxf(x, -15.0f), 15.0f);
    float e = __expf(2.0f * xc);
    return (e - 1.0f) / (e + 1.0f);
}

// Zero the state|new_state|deg|flags region
__global__ __launch_bounds__(256)
void k_init(float4* __restrict__ p, int n4) {
    int i = blockIdx.x * 256 + threadIdx.x;
    if (i < n4) p[i] = make_float4(0.f, 0.f, 0.f, 0.f);
}

// ---- CSR construction (counting sort by src) ----
__global__ __launch_bounds__(256)
void k_hist(const int* __restrict__ src, int* __restrict__ deg, int E) {
    int e = blockIdx.x * 256 + threadIdx.x;
    if (e < E) atomicAdd(&deg[src[e]], 1);
}

// Single-block scan, one pass
__global__ __launch_bounds__(1024)
void k_scan(const int* __restrict__ deg, int* __restrict__ cursor, int N) {
    __shared__ int wsum[16];
    const int t = threadIdx.x;
    const int lane = t & 63;
    const int wid = t >> 6;
    const int chunk = (N + 1023) / 1024;
    const int start = t * chunk;
    const int end = min(start + chunk, N);
    int sum = 0;
    for (int i = start; i < end; ++i) sum += deg[i];
    int incl = sum;
#pragma unroll
    for (int off = 1; off < 64; off <<= 1) {
        int u = __shfl_up(incl, off, 64);
        if (lane >= off) incl += u;
    }
    if (lane == 63) wsum[wid] = incl;
    __syncthreads();
    if (wid == 0) {
        int w = (lane < 16) ? wsum[lane] : 0;
        int wi = w;
#pragma unroll
        for (int off = 1; off < 16; off <<= 1) {
            int u = __shfl_up(wi, off, 64);
            if (lane >= off) wi += u;
        }
        if (lane < 16) wsum[lane] = wi - w;
    }
    __syncthreads();
    int run = incl - sum + wsum[wid];
    for (int i = start; i < end; ++i) {
        cursor[i] = run;
        run += deg[i];
    }
}

// pos[e] = sorted position; after this kernel cursor[n] = END of node n's run
__global__ __launch_bounds__(256)
void k_scatter(const int* __restrict__ src, const int* __restrict__ dst,
               int* __restrict__ cursor, int* __restrict__ pos,
               int* __restrict__ dstp, int* __restrict__ srcp, int E) {
    int e = blockIdx.x * 256 + threadIdx.x;
    if (e >= E) return;
    int s = src[e];
    int p = atomicAdd(&cursor[s], 1);
    pos[e] = p;
    dstp[p] = dst[e];
    srcp[p] = s;
}

// MFMA k_pre: pre[pos[e]] = fp16(bst1 + feat[e] @ Wst1[:64])
__global__ __launch_bounds__(256)
void k_pre(const float* __restrict__ feat, const float* __restrict__ Wst1,
           const float* __restrict__ bst1, const int* __restrict__ pos,
           _Float16* __restrict__ pre, int E) {
    __shared__ _Float16 sD[2][4][16][40];   // [parity][wave][row][col(pad 40)]
    const int t = threadIdx.x;
    const int wave = t >> 6;
    const int lane = t & 63;
    const int col = lane & 15;
    const int kg = lane >> 4;
    const int wbase = blockIdx.x * 256 + wave * 64;   // 64 rows per wave

    f16x8 Bh[2][2], Bl[2][2];
#pragma unroll
    for (int kt = 0; kt < 2; ++kt)
#pragma unroll
        for (int nt = 0; nt < 2; ++nt)
#pragma unroll
            for (int i = 0; i < 8; ++i) {
                float wv = Wst1[(size_t)(kt * 32 + kg * 8 + i) * H_DIM + nt * 16 + col];
                _Float16 hi = (_Float16)wv;
                Bh[kt][nt][i] = hi;
                Bl[kt][nt][i] = (_Float16)(wv - (float)hi);
            }
    float bias0 = bst1[col];
    float bias1 = bst1[16 + col];

#pragma unroll
    for (int mt = 0; mt < 4; ++mt) {
        const int row = wbase + mt * 16 + col;
        const bool rv = row < E;
        f16x8 Ah[2], Al[2];
#pragma unroll
        for (int kt = 0; kt < 2; ++kt) {
            float av[8];
            if (rv) {
                const float4* fp = reinterpret_cast<const float4*>(
                    feat + (size_t)row * D_FEAT + kt * 32 + kg * 8);
                float4 a0 = fp[0], a1 = fp[1];
                av[0] = a0.x; av[1] = a0.y; av[2] = a0.z; av[3] = a0.w;
                av[4] = a1.x; av[5] = a1.y; av[6] = a1.z; av[7] = a1.w;
            } else {
#pragma unroll
                for (int i = 0; i < 8; ++i) av[i] = 0.f;
            }
#pragma unroll
            for (int i = 0; i < 8; ++i) {
                _Float16 hi = (_Float16)av[i];
                Ah[kt][i] = hi;
                Al[kt][i] = (_Float16)(av[i] - (float)hi);
            }
        }
        f32x4 acc0 = {0.f, 0.f, 0.f, 0.f};
        f32x4 acc1 = {0.f, 0.f, 0.f, 0.f};
#pragma unroll
        for (int kt = 0; kt < 2; ++kt) {
            acc0 = __builtin_amdgcn_mfma_f32_16x16x32_f16(Ah[kt], Bh[kt][0], acc0, 0, 0, 0);
            acc0 = __builtin_amdgcn_mfma_f32_16x16x32_f16(Al[kt], Bh[kt][0], acc0, 0, 0, 0);
            acc0 = __builtin_amdgcn_mfma_f32_16x16x32_f16(Ah[kt], Bl[kt][0], acc0, 0, 0, 0);
            acc1 = __builtin_amdgcn_mfma_f32_16x16x32_f16(Ah[kt], Bh[kt][1], acc1, 0, 0, 0);
            acc1 = __builtin_amdgcn_mfma_f32_16x16x32_f16(Al[kt], Bh[kt][1], acc1, 0, 0, 0);
            acc1 = __builtin_amdgcn_mfma_f32_16x16x32_f16(Ah[kt], Bl[kt][1], acc1, 0, 0, 0);
        }
        const int par = mt & 1;
#pragma unroll
        for (int r = 0; r < 4; ++r) {
            sD[par][wave][kg * 4 + r][col] = (_Float16)(acc0[r] + bias0);
            sD[par][wave][kg * 4 + r][16 + col] = (_Float16)(acc1[r] + bias1);
        }
        __syncthreads();
        if (rv) {
            int p = pos[row];
            f16x8 v;
#pragma unroll
            for (int i = 0; i < 8; ++i) v[i] = sD[par][wave][col][kg * 8 + i];
            *reinterpret_cast<f16x8*>(pre + (size_t)p * H_DIM + kg * 8) = v;
        }
    }
}

// Fused: edge MLP + parallel in-block segmented sum -> new_state.
// LDS diet: transposed sres [16][257] + packed segment arrays -> 19.5KB
// -> 8 blocks/CU (32 waves, was 24). Arithmetic/order identical to round 14.
__global__ __launch_bounds__(256, 8)
void k_edge(const _Float16* __restrict__ pre, const _Float16* __restrict__ nodeH16,
            const int* __restrict__ dstp, const int* __restrict__ srcp,
            const int* __restrict__ rowend, const float* __restrict__ Wst2,
            const float* __restrict__ bst2, float* __restrict__ new_state,
            const int* __restrict__ flags, int it, int E) {
#pragma unroll
    for (int j = 0; j < MAX_IT; ++j)
        if (j < it && flags[2 + j] == 0) return;  // converged earlier -> frozen
    __shared__ float sres[16][257];   // [dim][edge]: writer conflict-free, reader stride-1
    __shared__ int ssrc[256];
    __shared__ int segA[256];         // (node<<8) | start
    __shared__ int segB[256];         // (en<<1) | writeflag
    __shared__ int nseg;
    const int t = threadIdx.x;
    const int base = blockIdx.x * 256;
    const int ep = base + t;
    const bool valid = ep < E;
    if (t == 0) nseg = 0;

    int s = valid ? srcp[ep] : (int)0x80000000;
    ssrc[t] = s;
    int re = valid ? rowend[s] : 0;   // speculative prefetch, used in head phase

    if (valid) {
        half8 n0, n1, n2, n3;
        const bool useH = (it != 0);
        if (useH) {
            int d = dstp[ep];
            const half8* np = reinterpret_cast<const half8*>(nodeH16 + (size_t)d * H_DIM);
            n0 = np[0]; n1 = np[1]; n2 = np[2]; n3 = np[3];
        }
        const half8* pp = reinterpret_cast<const half8*>(pre + (size_t)ep * H_DIM);
        half8 p0 = pp[0], p1 = pp[1], p2 = pp[2], p3 = pp[3];
        float h[H_DIM];
        if (useH) {
#pragma unroll
            for (int k = 0; k < 8; ++k) {
                h[k]      = fast_tanh((float)p0[k] + (float)n0[k]);
                h[8 + k]  = fast_tanh((float)p1[k] + (float)n1[k]);
                h[16 + k] = fast_tanh((float)p2[k] + (float)n2[k]);
                h[24 + k] = fast_tanh((float)p3[k] + (float)n3[k]);
            }
        } else {  // it==0: state0 = 0 -> nodeH = 0
#pragma unroll
            for (int k = 0; k < 8; ++k) {
                h[k]      = fast_tanh((float)p0[k]);
                h[8 + k]  = fast_tanh((float)p1[k]);
                h[16 + k] = fast_tanh((float)p2[k]);
                h[24 + k] = fast_tanh((float)p3[k]);
            }
        }
        float r[S_DIM];
#pragma unroll
        for (int i = 0; i < S_DIM; ++i) r[i] = bst2[i];
#pragma unroll
        for (int j = 0; j < H_DIM; ++j) {
            const float* w = Wst2 + (size_t)j * S_DIM;  // wave-uniform -> s_load
            float hj = h[j];
#pragma unroll
            for (int i = 0; i < S_DIM; ++i) r[i] = fmaf(hj, w[i], r[i]);
        }
#pragma unroll
        for (int i = 0; i < S_DIM; ++i) sres[i][t] = fast_tanh(r[i]);
    }
    __syncthreads();

    bool head = valid && ((t == 0) || (ssrc[t - 1] != s));
    if (head) {
        int slot = atomicAdd(&nseg, 1);
        int en = re - base; if (en > 256) en = 256;
        bool tS = (t > 0) || (ep == 0) || (srcp[ep - 1] != s);
        bool tE = (re <= base + 256);
        segA[slot] = (s << 8) | t;
        segB[slot] = (en << 1) | ((tS && tE) ? 1 : 0);
    }
    __syncthreads();

    int ns = nseg;
    for (int w = t; w < ns * 16; w += 256) {
        int slot = w >> 4;
        int dim = w & 15;
        int a_ = segA[slot];
        int b_ = segB[slot];
        int st = a_ & 255;
        int node = a_ >> 8;
        int en = b_ >> 1;
        float a = 0.f;
        for (int i = st; i < en; ++i) a += sres[dim][i];
        float* p = new_state + (size_t)node * S_DIM + dim;
        if (b_ & 1) *p = a;
        else atomicAdd(p, a);
    }
}

// 4 threads/node (iterations 0..3 only)
__global__ __launch_bounds__(256)
void k_node(float* __restrict__ state, float* __restrict__ new_state,
            _Float16* __restrict__ nodeH16, const float* __restrict__ Wst1,
            int* __restrict__ flags, int it, int N) {
#pragma unroll
    for (int j = 0; j < MAX_IT; ++j)
        if (j < it && flags[2 + j] == 0) return;
    int tt = blockIdx.x * 256 + threadIdx.x;
    int n = tt >> 2;
    int q = tt & 3;
    if (n >= N) return;
    float4* nsp = reinterpret_cast<float4*>(new_state + (size_t)n * S_DIM);
    float4* sp = reinterpret_cast<float4*>(state + (size_t)n * S_DIM);
    float4 acc = nsp[q];
    float4 old = sp[q];
    float dx = acc.x - old.x, dy = acc.y - old.y, dz = acc.z - old.z, dw = acc.w - old.w;
    float d2 = dx * dx + dy * dy + dz * dz + dw * dw;
    sp[q] = acc;
    nsp[q] = make_float4(0.f, 0.f, 0.f, 0.f);
    d2 += __shfl_xor(d2, 1);
    d2 += __shfl_xor(d2, 2);
    if (q == 0 && d2 + 1e-10f > 1e-4f) flags[2 + it] = 1;  // benign racy store

    float st[S_DIM];
    st[q * 4 + 0] = acc.x; st[q * 4 + 1] = acc.y; st[q * 4 + 2] = acc.z; st[q * 4 + 3] = acc.w;
#pragma unroll
    for (int m = 1; m < 4; ++m) {
        int qs = q ^ m;
        st[qs * 4 + 0] = __shfl_xor(acc.x, m);
        st[qs * 4 + 1] = __shfl_xor(acc.y, m);
        st[qs * 4 + 2] = __shfl_xor(acc.z, m);
        st[qs * 4 + 3] = __shfl_xor(acc.w, m);
    }
    float hh[8];
#pragma unroll
    for (int j = 0; j < 8; ++j) hh[j] = 0.f;
#pragma unroll
    for (int k = 0; k < S_DIM; ++k) {
        const float* w = Wst1 + (size_t)(D_FEAT + k) * H_DIM + q * 8;
        float sk = st[k];
#pragma unroll
        for (int j = 0; j < 8; ++j) hh[j] = fmaf(sk, w[j], hh[j]);
    }
    half8 hv;
#pragma unroll
    for (int j = 0; j < 8; ++j) hv[j] = (_Float16)hh[j];
    *reinterpret_cast<half8*>(nodeH16 + (size_t)n * H_DIM + q * 8) = hv;
}

// Final: output MLP + softmax (source = new_state unless frozen earlier)
__global__ __launch_bounds__(256)
void k_out(const float* __restrict__ state, const float* __restrict__ new_state,
           const int* __restrict__ flags, const float* __restrict__ Wout1,
           const float* __restrict__ bout1, const float* __restrict__ Wout2,
           const float* __restrict__ bout2, float* __restrict__ out, int N) {
    bool frozen = false;
#pragma unroll
    for (int j = 0; j < MAX_IT - 1; ++j)
        if (flags[2 + j] == 0) frozen = true;
    const float* src = frozen ? state : new_state;

    int n = blockIdx.x * 256 + threadIdx.x;
    if (n >= N) return;
    float st[S_DIM];
    const float4* sp = reinterpret_cast<const float4*>(src + (size_t)n * S_DIM);
    float4 v0 = sp[0], v1 = sp[1], v2 = sp[2], v3 = sp[3];
    st[0] = v0.x; st[1] = v0.y; st[2] = v0.z; st[3] = v0.w;
    st[4] = v1.x; st[5] = v1.y; st[6] = v1.z; st[7] = v1.w;
    st[8] = v2.x; st[9] = v2.y; st[10] = v2.z; st[11] = v2.w;
    st[12] = v3.x; st[13] = v3.y; st[14] = v3.z; st[15] = v3.w;

    float h[H_DIM];
#pragma unroll
    for (int j = 0; j < H_DIM; ++j) {
        float acc = bout1[j];
#pragma unroll
        for (int k = 0; k < S_DIM; ++k) acc = fmaf(st[k], Wout1[(size_t)k * H_DIM + j], acc);
        h[j] = fast_tanh(acc);
    }
    float l[OUT_DIM];
#pragma unroll
    for (int i = 0; i < OUT_DIM; ++i) l[i] = bout2[i];
#pragma unroll
    for (int j = 0; j < H_DIM; ++j) {
        float hj = h[j];
#pragma unroll
        for (int i = 0; i < OUT_DIM; ++i) l[i] = fmaf(hj, Wout2[(size_t)j * OUT_DIM + i], l[i]);
    }
    float m = l[0];
#pragma unroll
    for (int i = 1; i < OUT_DIM; ++i) m = fmaxf(m, l[i]);
    float sum = 0.0f;
#pragma unroll
    for (int i = 0; i < OUT_DIM; ++i) {
        float tv = __expf(l[i] - m);
        l[i] = tv;
        sum += tv;
    }
    float inv = 1.0f / sum;
    float4* op = reinterpret_cast<float4*>(out + (size_t)n * OUT_DIM);
    op[0] = make_float4(l[0] * inv, l[1] * inv, l[2] * inv, l[3] * inv);
    op[1] = make_float4(l[4] * inv, l[5] * inv, l[6] * inv, l[7] * inv);
    op[2] = make_float4(l[8] * inv, l[9] * inv, l[10] * inv, l[11] * inv);
    op[3] = make_float4(l[12] * inv, l[13] * inv, l[14] * inv, l[15] * inv);
}

extern "C" void kernel_launch(void* const* d_in, const int* in_sizes, int n_in,
                              void* d_out, int out_size, void* d_ws, size_t ws_size,
                              hipStream_t stream) {
    const float* edge_feat = (const float*)d_in[0];
    const float* Wst1 = (const float*)d_in[1];
    const float* bst1 = (const float*)d_in[2];
    const float* Wst2 = (const float*)d_in[3];
    const float* bst2 = (const float*)d_in[4];
    const float* Wout1 = (const float*)d_in[5];
    const float* bout1 = (const float*)d_in[6];
    const float* Wout2 = (const float*)d_in[7];
    const float* bout2 = (const float*)d_in[8];
    const int* esrc = (const int*)d_in[9];
    const int* edst = (const int*)d_in[10];
    const int E = in_sizes[9];
    const int N = out_size / OUT_DIM;
    float* out = (float*)d_out;

    // ws layout (zeroed region first, contiguous):
    // state[N*16] | new_state[N*16] | deg[N] | flags[8]
    // then: pre (_Float16, E*32) | nodeH16 (_Float16, N*32) | pos[E] | dstp[E] | srcp[E] | cursor[N]
    float* state = (float*)d_ws;
    float* new_state = state + (size_t)N * S_DIM;
    int* deg = (int*)(new_state + (size_t)N * S_DIM);
    int* flags = deg + N;
    _Float16* pre = (_Float16*)(flags + 8);
    _Float16* nodeH16 = pre + (size_t)E * H_DIM;
    int* pos = (int*)(nodeH16 + (size_t)N * H_DIM);
    int* dstp = pos + E;
    int* srcp = dstp + E;
    int* cursor = srcp + E;

    int zdw = N * (S_DIM * 2 + 1) + 8;
    int zn4 = (zdw + 3) / 4;
    int zbl = (zn4 + 255) / 256;
    k_init<<<zbl, 256, 0, stream>>>((float4*)d_ws, zn4);

    int ebl = (E + 255) / 256;
    int nbl = (N + 255) / 256;
    int rbl = (N * 4 + 255) / 256;

    k_hist<<<ebl, 256, 0, stream>>>(esrc, deg, E);
    k_scan<<<1, 1024, 0, stream>>>(deg, cursor, N);
    k_scatter<<<ebl, 256, 0, stream>>>(esrc, edst, cursor, pos, dstp, srcp, E);
    k_pre<<<ebl, 256, 0, stream>>>(edge_feat, Wst1, bst1, pos, pre, E);

    for (int it = 0; it < MAX_IT; ++it) {
        k_edge<<<ebl, 256, 0, stream>>>(pre, nodeH16, dstp, srcp, cursor, Wst2, bst2,
                                        new_state, flags, it, E);
        if (it < MAX_IT - 1)
            k_node<<<rbl, 256, 0, stream>>>(state, new_state, nodeH16, Wst1, flags, it, N);
    }
    k_out<<<nbl, 256, 0, stream>>>(state, new_state, flags, Wout1, bout1,
                                   Wout2, bout2, out, N);
}

// Round 16
// 268.652 us; speedup vs baseline: 1.0560x; 1.0560x over previous
//
#include <hip/hip_runtime.h>
#include <cstddef>

#define D_FEAT 64
#define S_DIM 16
#define H_DIM 32
#define OUT_DIM 16
#define MAX_IT 5

typedef _Float16 half8 __attribute__((ext_vector_type(8)));
typedef _Float16 f16x8 __attribute__((ext_vector_type(8)));
typedef float f32x4 __attribute__((ext_vector_type(4)));

__device__ __forceinline__ float fast_tanh(float x) {
    float xc = fminf(fmaxf(x, -15.0f), 15.0f);
    float e = __expf(2.0f * xc);
    return (e - 1.0f) / (e + 1.0f);
}

// Zero the state|new_state|deg|flags region
__global__ __launch_bounds__(256)
void k_init(float4* __restrict__ p, int n4) {
    int i = blockIdx.x * 256 + threadIdx.x;
    if (i < n4) p[i] = make_float4(0.f, 0.f, 0.f, 0.f);
}

// ---- CSR construction (counting sort by src) ----
__global__ __launch_bounds__(256)
void k_hist(const int* __restrict__ src, int* __restrict__ deg, int E) {
    int e = blockIdx.x * 256 + threadIdx.x;
    if (e < E) atomicAdd(&deg[src[e]], 1);
}

// Single-block scan, one pass
__global__ __launch_bounds__(1024)
void k_scan(const int* __restrict__ deg, int* __restrict__ cursor, int N) {
    __shared__ int wsum[16];
    const int t = threadIdx.x;
    const int lane = t & 63;
    const int wid = t >> 6;
    const int chunk = (N + 1023) / 1024;
    const int start = t * chunk;
    const int end = min(start + chunk, N);
    int sum = 0;
    for (int i = start; i < end; ++i) sum += deg[i];
    int incl = sum;
#pragma unroll
    for (int off = 1; off < 64; off <<= 1) {
        int u = __shfl_up(incl, off, 64);
        if (lane >= off) incl += u;
    }
    if (lane == 63) wsum[wid] = incl;
    __syncthreads();
    if (wid == 0) {
        int w = (lane < 16) ? wsum[lane] : 0;
        int wi = w;
#pragma unroll
        for (int off = 1; off < 16; off <<= 1) {
            int u = __shfl_up(wi, off, 64);
            if (lane >= off) wi += u;
        }
        if (lane < 16) wsum[lane] = wi - w;
    }
    __syncthreads();
    int run = incl - sum + wsum[wid];
    for (int i = start; i < end; ++i) {
        cursor[i] = run;
        run += deg[i];
    }
}

// pos[e] = sorted position; after this kernel cursor[n] = END of node n's run
__global__ __launch_bounds__(256)
void k_scatter(const int* __restrict__ src, const int* __restrict__ dst,
               int* __restrict__ cursor, int* __restrict__ pos,
               int* __restrict__ dstp, int* __restrict__ srcp, int E) {
    int e = blockIdx.x * 256 + threadIdx.x;
    if (e >= E) return;
    int s = src[e];
    int p = atomicAdd(&cursor[s], 1);
    pos[e] = p;
    dstp[p] = dst[e];
    srcp[p] = s;
}

// MFMA k_pre: pre[pos[e]] = fp16(bst1 + feat[e] @ Wst1[:64])
// GEMM [E x 64] @ [64 x 32] on v_mfma_f32_16x16x32_f16 with hi/lo fp16 split.
__global__ __launch_bounds__(256)
void k_pre(const float* __restrict__ feat, const float* __restrict__ Wst1,
           const float* __restrict__ bst1, const int* __restrict__ pos,
           _Float16* __restrict__ pre, int E) {
    __shared__ _Float16 sD[2][4][16][40];   // [parity][wave][row][col(pad 40)]
    const int t = threadIdx.x;
    const int wave = t >> 6;
    const int lane = t & 63;
    const int col = lane & 15;
    const int kg = lane >> 4;
    const int wbase = blockIdx.x * 256 + wave * 64;   // 64 rows per wave

    f16x8 Bh[2][2], Bl[2][2];
#pragma unroll
    for (int kt = 0; kt < 2; ++kt)
#pragma unroll
        for (int nt = 0; nt < 2; ++nt)
#pragma unroll
            for (int i = 0; i < 8; ++i) {
                float wv = Wst1[(size_t)(kt * 32 + kg * 8 + i) * H_DIM + nt * 16 + col];
                _Float16 hi = (_Float16)wv;
                Bh[kt][nt][i] = hi;
                Bl[kt][nt][i] = (_Float16)(wv - (float)hi);
            }
    float bias0 = bst1[col];
    float bias1 = bst1[16 + col];

#pragma unroll
    for (int mt = 0; mt < 4; ++mt) {
        const int row = wbase + mt * 16 + col;
        const bool rv = row < E;
        f16x8 Ah[2], Al[2];
#pragma unroll
        for (int kt = 0; kt < 2; ++kt) {
            float av[8];
            if (rv) {
                const float4* fp = reinterpret_cast<const float4*>(
                    feat + (size_t)row * D_FEAT + kt * 32 + kg * 8);
                float4 a0 = fp[0], a1 = fp[1];
                av[0] = a0.x; av[1] = a0.y; av[2] = a0.z; av[3] = a0.w;
                av[4] = a1.x; av[5] = a1.y; av[6] = a1.z; av[7] = a1.w;
            } else {
#pragma unroll
                for (int i = 0; i < 8; ++i) av[i] = 0.f;
            }
#pragma unroll
            for (int i = 0; i < 8; ++i) {
                _Float16 hi = (_Float16)av[i];
                Ah[kt][i] = hi;
                Al[kt][i] = (_Float16)(av[i] - (float)hi);
            }
        }
        f32x4 acc0 = {0.f, 0.f, 0.f, 0.f};
        f32x4 acc1 = {0.f, 0.f, 0.f, 0.f};
#pragma unroll
        for (int kt = 0; kt < 2; ++kt) {
            acc0 = __builtin_amdgcn_mfma_f32_16x16x32_f16(Ah[kt], Bh[kt][0], acc0, 0, 0, 0);
            acc0 = __builtin_amdgcn_mfma_f32_16x16x32_f16(Al[kt], Bh[kt][0], acc0, 0, 0, 0);
            acc0 = __builtin_amdgcn_mfma_f32_16x16x32_f16(Ah[kt], Bl[kt][0], acc0, 0, 0, 0);
            acc1 = __builtin_amdgcn_mfma_f32_16x16x32_f16(Ah[kt], Bh[kt][1], acc1, 0, 0, 0);
            acc1 = __builtin_amdgcn_mfma_f32_16x16x32_f16(Al[kt], Bh[kt][1], acc1, 0, 0, 0);
            acc1 = __builtin_amdgcn_mfma_f32_16x16x32_f16(Ah[kt], Bl[kt][1], acc1, 0, 0, 0);
        }
        const int par = mt & 1;
#pragma unroll
        for (int r = 0; r < 4; ++r) {
            sD[par][wave][kg * 4 + r][col] = (_Float16)(acc0[r] + bias0);
            sD[par][wave][kg * 4 + r][16 + col] = (_Float16)(acc1[r] + bias1);
        }
        __syncthreads();
        if (rv) {
            int p = pos[row];
            f16x8 v;
#pragma unroll
            for (int i = 0; i < 8; ++i) v[i] = sD[par][wave][col][kg * 8 + i];
            *reinterpret_cast<f16x8*>(pre + (size_t)p * H_DIM + kg * 8) = v;
        }
    }
}

// Fused: edge MLP + parallel in-block segmented sum -> new_state
__global__ __launch_bounds__(256)
void k_edge(const _Float16* __restrict__ pre, const _Float16* __restrict__ nodeH16,
            const int* __restrict__ dstp, const int* __restrict__ srcp,
            const int* __restrict__ rowend, const float* __restrict__ Wst2,
            const float* __restrict__ bst2, float* __restrict__ new_state,
            const int* __restrict__ flags, int it, int E) {
#pragma unroll
    for (int j = 0; j < MAX_IT; ++j)
        if (j < it && flags[2 + j] == 0) return;  // converged earlier -> frozen
    __shared__ float sres[256][17];
    __shared__ int ssrc[256];
    __shared__ int segnode[256];
    __shared__ int segstart[256];
    __shared__ int segend[256];
    __shared__ int segflag[256];
    __shared__ int nseg;
    const int t = threadIdx.x;
    const int base = blockIdx.x * 256;
    const int ep = base + t;
    const bool valid = ep < E;
    if (t == 0) nseg = 0;

    int s = valid ? srcp[ep] : (int)0x80000000;
    ssrc[t] = s;
    int re = valid ? rowend[s] : 0;   // speculative prefetch, used in head phase

    if (valid) {
        half8 n0, n1, n2, n3;
        const bool useH = (it != 0);
        if (useH) {
            int d = dstp[ep];
            const half8* np = reinterpret_cast<const half8*>(nodeH16 + (size_t)d * H_DIM);
            n0 = np[0]; n1 = np[1]; n2 = np[2]; n3 = np[3];
        }
        const half8* pp = reinterpret_cast<const half8*>(pre + (size_t)ep * H_DIM);
        half8 p0 = pp[0], p1 = pp[1], p2 = pp[2], p3 = pp[3];
        float h[H_DIM];
        if (useH) {
#pragma unroll
            for (int k = 0; k < 8; ++k) {
                h[k]      = fast_tanh((float)p0[k] + (float)n0[k]);
                h[8 + k]  = fast_tanh((float)p1[k] + (float)n1[k]);
                h[16 + k] = fast_tanh((float)p2[k] + (float)n2[k]);
                h[24 + k] = fast_tanh((float)p3[k] + (float)n3[k]);
            }
        } else {  // it==0: state0 = 0 -> nodeH = 0
#pragma unroll
            for (int k = 0; k < 8; ++k) {
                h[k]      = fast_tanh((float)p0[k]);
                h[8 + k]  = fast_tanh((float)p1[k]);
                h[16 + k] = fast_tanh((float)p2[k]);
                h[24 + k] = fast_tanh((float)p3[k]);
            }
        }
        float r[S_DIM];
#pragma unroll
        for (int i = 0; i < S_DIM; ++i) r[i] = bst2[i];
#pragma unroll
        for (int j = 0; j < H_DIM; ++j) {
            const float* w = Wst2 + (size_t)j * S_DIM;  // wave-uniform -> s_load
            float hj = h[j];
#pragma unroll
            for (int i = 0; i < S_DIM; ++i) r[i] = fmaf(hj, w[i], r[i]);
        }
#pragma unroll
        for (int i = 0; i < S_DIM; ++i) sres[t][i] = fast_tanh(r[i]);
    }
    __syncthreads();

    bool head = valid && ((t == 0) || (ssrc[t - 1] != s));
    if (head) {
        int slot = atomicAdd(&nseg, 1);
        int en = re - base; if (en > 256) en = 256;
        bool tS = (t > 0) || (ep == 0) || (srcp[ep - 1] != s);
        bool tE = (re <= base + 256);
        segnode[slot] = s;
        segstart[slot] = t;
        segend[slot] = en;
        segflag[slot] = (tS && tE) ? 1 : 0;
    }
    __syncthreads();

    int ns = nseg;
    for (int w = t; w < ns * 16; w += 256) {
        int slot = w >> 4;
        int dim = w & 15;
        int st = segstart[slot];
        int en = segend[slot];
        int node = segnode[slot];
        float a = 0.f;
        for (int i = st; i < en; ++i) a += sres[i][dim];
        float* p = new_state + (size_t)node * S_DIM + dim;
        if (segflag[slot]) *p = a;
        else atomicAdd(p, a);
    }
}

// 4 threads/node (iterations 0..3 only)
__global__ __launch_bounds__(256)
void k_node(float* __restrict__ state, float* __restrict__ new_state,
            _Float16* __restrict__ nodeH16, const float* __restrict__ Wst1,
            int* __restrict__ flags, int it, int N) {
#pragma unroll
    for (int j = 0; j < MAX_IT; ++j)
        if (j < it && flags[2 + j] == 0) return;
    int tt = blockIdx.x * 256 + threadIdx.x;
    int n = tt >> 2;
    int q = tt & 3;
    if (n >= N) return;
    float4* nsp = reinterpret_cast<float4*>(new_state + (size_t)n * S_DIM);
    float4* sp = reinterpret_cast<float4*>(state + (size_t)n * S_DIM);
    float4 acc = nsp[q];
    float4 old = sp[q];
    float dx = acc.x - old.x, dy = acc.y - old.y, dz = acc.z - old.z, dw = acc.w - old.w;
    float d2 = dx * dx + dy * dy + dz * dz + dw * dw;
    sp[q] = acc;
    nsp[q] = make_float4(0.f, 0.f, 0.f, 0.f);
    d2 += __shfl_xor(d2, 1);
    d2 += __shfl_xor(d2, 2);
    if (q == 0 && d2 + 1e-10f > 1e-4f) flags[2 + it] = 1;  // benign racy store

    float st[S_DIM];
    st[q * 4 + 0] = acc.x; st[q * 4 + 1] = acc.y; st[q * 4 + 2] = acc.z; st[q * 4 + 3] = acc.w;
#pragma unroll
    for (int m = 1; m < 4; ++m) {
        int qs = q ^ m;
        st[qs * 4 + 0] = __shfl_xor(acc.x, m);
        st[qs * 4 + 1] = __shfl_xor(acc.y, m);
        st[qs * 4 + 2] = __shfl_xor(acc.z, m);
        st[qs * 4 + 3] = __shfl_xor(acc.w, m);
    }
    float hh[8];
#pragma unroll
    for (int j = 0; j < 8; ++j) hh[j] = 0.f;
#pragma unroll
    for (int k = 0; k < S_DIM; ++k) {
        const float* w = Wst1 + (size_t)(D_FEAT + k) * H_DIM + q * 8;
        float sk = st[k];
#pragma unroll
        for (int j = 0; j < 8; ++j) hh[j] = fmaf(sk, w[j], hh[j]);
    }
    half8 hv;
#pragma unroll
    for (int j = 0; j < 8; ++j) hv[j] = (_Float16)hh[j];
    *reinterpret_cast<half8*>(nodeH16 + (size_t)n * H_DIM + q * 8) = hv;
}

// Final: output MLP + softmax (source = new_state unless frozen earlier)
__global__ __launch_bounds__(256)
void k_out(const float* __restrict__ state, const float* __restrict__ new_state,
           const int* __restrict__ flags, const float* __restrict__ Wout1,
           const float* __restrict__ bout1, const float* __restrict__ Wout2,
           const float* __restrict__ bout2, float* __restrict__ out, int N) {
    bool frozen = false;
#pragma unroll
    for (int j = 0; j < MAX_IT - 1; ++j)
        if (flags[2 + j] == 0) frozen = true;
    const float* src = frozen ? state : new_state;

    int n = blockIdx.x * 256 + threadIdx.x;
    if (n >= N) return;
    float st[S_DIM];
    const float4* sp = reinterpret_cast<const float4*>(src + (size_t)n * S_DIM);
    float4 v0 = sp[0], v1 = sp[1], v2 = sp[2], v3 = sp[3];
    st[0] = v0.x; st[1] = v0.y; st[2] = v0.z; st[3] = v0.w;
    st[4] = v1.x; st[5] = v1.y; st[6] = v1.z; st[7] = v1.w;
    st[8] = v2.x; st[9] = v2.y; st[10] = v2.z; st[11] = v2.w;
    st[12] = v3.x; st[13] = v3.y; st[14] = v3.z; st[15] = v3.w;

    float h[H_DIM];
#pragma unroll
    for (int j = 0; j < H_DIM; ++j) {
        float acc = bout1[j];
#pragma unroll
        for (int k = 0; k < S_DIM; ++k) acc = fmaf(st[k], Wout1[(size_t)k * H_DIM + j], acc);
        h[j] = fast_tanh(acc);
    }
    float l[OUT_DIM];
#pragma unroll
    for (int i = 0; i < OUT_DIM; ++i) l[i] = bout2[i];
#pragma unroll
    for (int j = 0; j < H_DIM; ++j) {
        float hj = h[j];
#pragma unroll
        for (int i = 0; i < OUT_DIM; ++i) l[i] = fmaf(hj, Wout2[(size_t)j * OUT_DIM + i], l[i]);
    }
    float m = l[0];
#pragma unroll
    for (int i = 1; i < OUT_DIM; ++i) m = fmaxf(m, l[i]);
    float sum = 0.0f;
#pragma unroll
    for (int i = 0; i < OUT_DIM; ++i) {
        float tv = __expf(l[i] - m);
        l[i] = tv;
        sum += tv;
    }
    float inv = 1.0f / sum;
    float4* op = reinterpret_cast<float4*>(out + (size_t)n * OUT_DIM);
    op[0] = make_float4(l[0] * inv, l[1] * inv, l[2] * inv, l[3] * inv);
    op[1] = make_float4(l[4] * inv, l[5] * inv, l[6] * inv, l[7] * inv);
    op[2] = make_float4(l[8] * inv, l[9] * inv, l[10] * inv, l[11] * inv);
    op[3] = make_float4(l[12] * inv, l[13] * inv, l[14] * inv, l[15] * inv);
}

extern "C" void kernel_launch(void* const* d_in, const int* in_sizes, int n_in,
                              void* d_out, int out_size, void* d_ws, size_t ws_size,
                              hipStream_t stream) {
    const float* edge_feat = (const float*)d_in[0];
    const float* Wst1 = (const float*)d_in[1];
    const float* bst1 = (const float*)d_in[2];
    const float* Wst2 = (const float*)d_in[3];
    const float* bst2 = (const float*)d_in[4];
    const float* Wout1 = (const float*)d_in[5];
    const float* bout1 = (const float*)d_in[6];
    const float* Wout2 = (const float*)d_in[7];
    const float* bout2 = (const float*)d_in[8];
    const int* esrc = (const int*)d_in[9];
    const int* edst = (const int*)d_in[10];
    const int E = in_sizes[9];
    const int N = out_size / OUT_DIM;
    float* out = (float*)d_out;

    // ws layout (zeroed region first, contiguous):
    // state[N*16] | new_state[N*16] | deg[N] | flags[8]
    // then: pre (_Float16, E*32) | nodeH16 (_Float16, N*32) | pos[E] | dstp[E] | srcp[E] | cursor[N]
    float* state = (float*)d_ws;
    float* new_state = state + (size_t)N * S_DIM;
    int* deg = (int*)(new_state + (size_t)N * S_DIM);
    int* flags = deg + N;
    _Float16* pre = (_Float16*)(flags + 8);
    _Float16* nodeH16 = pre + (size_t)E * H_DIM;
    int* pos = (int*)(nodeH16 + (size_t)N * H_DIM);
    int* dstp = pos + E;
    int* srcp = dstp + E;
    int* cursor = srcp + E;

    int zdw = N * (S_DIM * 2 + 1) + 8;
    int zn4 = (zdw + 3) / 4;
    int zbl = (zn4 + 255) / 256;
    k_init<<<zbl, 256, 0, stream>>>((float4*)d_ws, zn4);

    int ebl = (E + 255) / 256;
    int nbl = (N + 255) / 256;
    int rbl = (N * 4 + 255) / 256;

    k_hist<<<ebl, 256, 0, stream>>>(esrc, deg, E);
    k_scan<<<1, 1024, 0, stream>>>(deg, cursor, N);
    k_scatter<<<ebl, 256, 0, stream>>>(esrc, edst, cursor, pos, dstp, srcp, E);
    k_pre<<<ebl, 256, 0, stream>>>(edge_feat, Wst1, bst1, pos, pre, E);

    for (int it = 0; it < MAX_IT; ++it) {
        k_edge<<<ebl, 256, 0, stream>>>(pre, nodeH16, dstp, srcp, cursor, Wst2, bst2,
                                        new_state, flags, it, E);
        if (it < MAX_IT - 1)
            k_node<<<rbl, 256, 0, stream>>>(state, new_state, nodeH16, Wst1, flags, it, N);
    }
    k_out<<<nbl, 256, 0, stream>>>(state, new_state, flags, Wout1, bout1,
                                   Wout2, bout2, out, N);
}